// Round 10
// baseline (7412.699 us; speedup 1.0000x reference)
//
#include <hip/hip_runtime.h>
#include <hip/hip_bf16.h>
#include <stdint.h>

typedef __bf16 bf16;
typedef __attribute__((ext_vector_type(8))) __bf16 bf16x8;
typedef __attribute__((ext_vector_type(4))) float f32x4;
typedef __attribute__((ext_vector_type(2))) unsigned int u32x2;
typedef unsigned long long u64;

#define MFMA_B16(a,b,c) __builtin_amdgcn_mfma_f32_16x16x32_bf16((a),(b),(c),0,0,0)

// problem dims
#define BATCH  1024
#define NSTEPS 1024
#define OBS    32
#define ACTD   8
#define WIDTH  512
#define OUTS   ((NSTEPS+1)*OBS)
#define K0     128   // [y_hi 32 | y_lo 32 | act 8 | one@72 | zero-pad -> 128]
#define NGRP   32    // 32 groups x 4 members x 32 batch rows (2 tiles of 16)

// ws layout (bf16 element offsets for weights)
#define W0P_OFF 0
#define W0P_N   (WIDTH*K0)
#define W1_OFF  (W0P_OFF + W0P_N)
#define WBIG_N  (WIDTH*WIDTH)
#define W2_OFF  (W1_OFF + WBIG_N)
#define W3_OFF  (W2_OFF + WBIG_N)
#define W3_N    (OBS*WIDTH)
#define TAU_OFF (W3_OFF + W3_N)
// tagged mailboxes (u64 units, base at bf16-offset MBQ_OFF = byte 1213440):
//  H1: slot=(g*2+T)*4+j (0..255), 1024 u64 each -> [0, 262144)
//  DY: slot same,                  512 u64 each -> [262144, 393216)
#define MBQ_OFF     606720
#define DY_U64_BASE 262144
#define MB_U64_N    393216

#define LBAR() do{ asm volatile("s_waitcnt lgkmcnt(0)" ::: "memory"); \
                   __builtin_amdgcn_s_barrier(); \
                   __builtin_amdgcn_sched_barrier(0); }while(0)

__global__ void setup_kernel(const float* __restrict__ W0, const float* __restrict__ b0r,
                             const float* __restrict__ W1, const float* __restrict__ W2,
                             const float* __restrict__ W3,
                             const int* __restrict__ tau, bf16* __restrict__ wsb){
  int i = blockIdx.x*blockDim.x + threadIdx.x;
  int stride = gridDim.x*blockDim.x;
  for (int idx=i; idx<W0P_N; idx+=stride){
    int r = idx >> 7, c = idx & 127;
    float v = 0.0f;
    if (c < 32)       v = W0[r*40 + c];
    else if (c < 64)  v = W0[r*40 + (c-32)];
    else if (c < 72)  v = W0[r*40 + 32 + (c-64)];
    else if (c == 72) v = b0r[r];
    wsb[W0P_OFF+idx] = (bf16)v;
  }
  for (int idx=i; idx<WBIG_N; idx+=stride) wsb[W1_OFF+idx] = (bf16)W1[idx];
  for (int idx=i; idx<WBIG_N; idx+=stride) wsb[W2_OFF+idx] = (bf16)W2[idx];
  for (int idx=i; idx<W3_N;  idx+=stride) wsb[W3_OFF+idx] = (bf16)W3[idx];
  u64* mbq = (u64*)(wsb + MBQ_OFF);
  for (int idx=i; idx<MB_U64_N; idx+=stride) mbq[idx] = 0ull;   // tags=0 (!= any step)
  if (i==0){
    int ti = *tau;
    float tf;
    if (ti >= -1000000 && ti <= 1000000) tf = (float)ti;
    else { union {int q; float f;} u; u.q = ti; tf = u.f; }
    *(float*)(wsb + TAU_OFF) = tf;
  }
}

__device__ __forceinline__ float leaky(float v){ return v < 0.0f ? 0.01f*v : v; }

__device__ __forceinline__ uint32_t pk2(float a, float b){
  union { bf16 h; uint16_t u; } ua, ub; ua.h = (bf16)a; ub.h = (bf16)b;
  return (uint32_t)ua.u | ((uint32_t)ub.u << 16);
}

__global__ __launch_bounds__(512, 2)
void ode_kernel(const float* __restrict__ init_obs, const float* __restrict__ actions,
                const float* __restrict__ b1g, const float* __restrict__ b2g,
                const float* __restrict__ b3g,
                bf16* __restrict__ wsrw, float* __restrict__ out){
  const bf16* w0g = wsrw + W0P_OFF;
  const bf16* w1g = wsrw + W1_OFF;
  const bf16* w2g = wsrw + W2_OFF;
  const bf16* w3g = wsrw + W3_OFF;
  u64* mbq = (u64*)(wsrw + MBQ_OFF);
  const float tauf = *(const float*)(wsrw + TAU_OFF);

  __shared__ alignas(16) bf16 w0s[96*512];      // 96KB full W0, fragment order
  __shared__ alignas(16) bf16 w3s[8*512];       // 8KB  W3 own-K slice
  __shared__ alignas(16) bf16 hF0[16*WIDTH];    // 16KB h0 / h2 (shared by tiles)
  __shared__ alignas(16) bf16 hF1[16*WIDTH];    // 16KB h1 (shared by tiles)
  __shared__ alignas(16) bf16 xin0[16*K0];      // 4KB tile0
  __shared__ alignas(16) bf16 xin1[16*K0];      // 4KB tile1
  __shared__ alignas(16) float pr[8][16][20];   // 10KB l3 partials (shared)
  __shared__ float yS0[16][OBS];                // 2KB tile0 state
  __shared__ float yS1[16][OBS];                // 2KB tile1 state
  __shared__ int sdead;

  const int t    = threadIdx.x;
  const int lane = t & 63;
  const int wave = t >> 6;
  const int fm   = lane & 15;
  const int fk   = lane >> 4;
  const int b    = blockIdx.x;
  const int xcd  = b & 7, slot = b >> 3;       // 128 blocks, 16/XCD heuristic
  const int g    = xcd*4 + (slot >> 2);        // group 0..31
  const int j    = slot & 3;                   // member: out-col quarter
  const int gb0  = g * 32;
  const int pm0 = (j==0)?1:0, pm1 = (j<2)?2:1, pm2 = (j<3)?3:2;

  const int hbase1 = fm*WIDTH + ((fk*8) ^ (fm*8));
  const int xbase0 = fm*K0    + ((fk*8) ^ (fm*8));
  const int chi    = j*128 + wave*16 + fk*4;

  const f32x4 b1q = *(const f32x4*)&b1g[chi];
  const f32x4 b2q = *(const f32x4*)&b2g[chi];

  // ---- resident weights: W1/W2 quarter -> regs, pinned ----
  bf16x8 w1f[16], w2f[16];
  {
    const bf16* p1 = w1g + (size_t)(j*128 + wave*16 + fm)*WIDTH + fk*8;
    const bf16* p2 = w2g + (size_t)(j*128 + wave*16 + fm)*WIDTH + fk*8;
    #pragma unroll
    for (int kk=0; kk<16; kk++) w1f[kk] = *(const bf16x8*)(p1 + kk*32);
    #pragma unroll
    for (int kk=0; kk<16; kk++) w2f[kk] = *(const bf16x8*)(p2 + kk*32);
  }
  // ---- FULL W0 (3 k-steps) + own W3 K-slice -> LDS, fragment order ----
  {
    #pragma unroll
    for (int n=0; n<4; n++){
      const bf16* s0 = w0g + (size_t)((wave*4+n)*16 + fm)*K0 + fk*8;
      #pragma unroll
      for (int k=0; k<3; k++){
        bf16x8 v = *(const bf16x8*)(s0 + k*32);
        *(bf16x8*)&w0s[((wave*4+n)*3 + k)*512 + lane*8] = v;
      }
    }
    const int nt_ = wave & 1, q_ = wave >> 1;
    bf16x8 v3 = *(const bf16x8*)(w3g + (size_t)(nt_*16 + fm)*WIDTH + j*128 + q_*32 + fk*8);
    *(bf16x8*)&w3s[wave*512 + lane*8] = v3;
  }

  // update-phase constants
  const int urow = t >> 5, ucol = t & 31;
  const float b3v = b3g[ucol];
  float* const outp0 = out + (size_t)(gb0 + urow)*OUTS + ucol;
  float* const outp1 = outp0 + (size_t)16*OUTS;
  const int arow = (t >> 3) & 15, acol = t & 7;
  const float* const actp0 = actions + (size_t)(gb0 + arow)*(NSTEPS*ACTD) + acol;
  const float* const actp1 = actp0 + (size_t)16*NSTEPS*ACTD;
  const int swU    = (urow & 15) << 3;
  const int xin_yh = urow*K0 + (ucol ^ swU);
  const int xin_yl = urow*K0 + ((ucol + 32) ^ swU);
  const int xin_ac = arow*K0 + ((64 + acol) ^ ((arow & 15) << 3));

  // ---- init both tiles ----
  {
    if (t == 0) sdead = 0;
    #pragma unroll
    for (int q=0; q<(16*K0)/512; q++){ xin0[q*512 + t] = (bf16)0.0f; xin1[q*512 + t] = (bf16)0.0f; }
    __syncthreads();
    float yv0 = init_obs[(gb0 + urow)*OBS + ucol];
    float yv1 = init_obs[(gb0 + 16 + urow)*OBS + ucol];
    yS0[urow][ucol] = yv0;  yS1[urow][ucol] = yv1;
    if (j == 0){ outp0[0] = yv0; outp1[0] = yv1; }
    bf16 yh0 = (bf16)yv0, yh1 = (bf16)yv1;
    xin0[xin_yh] = yh0; xin0[xin_yl] = (bf16)(yv0 - (float)yh0);
    xin1[xin_yh] = yh1; xin1[xin_yl] = (bf16)(yv1 - (float)yh1);
    if (t < 128){ xin0[xin_ac] = (bf16)actp0[0]; xin1[xin_ac] = (bf16)actp1[0]; }
    if (t < 16){ int e = t*K0 + (72 ^ ((t&15)*8)); xin0[e] = (bf16)1.0f; xin1[e] = (bf16)1.0f; }
  }
  __syncthreads();

  #pragma unroll
  for (int kk=0; kk<16; kk++){ asm volatile("" : "+v"(w1f[kk])); }
  #pragma unroll
  for (int kk=0; kk<16; kk++){ asm volatile("" : "+v"(w2f[kk])); }

  // ---- L01: replicated l0 -> hF0 -> own-quarter l1 -> tagged publish ----
  #define L01PHASE(T, XINB, OWNQ, S1) do{ \
    _Pragma("unroll") \
    for (int n=0; n<4; n++){ \
      f32x4 acc_ = {0,0,0,0}; \
      _Pragma("unroll") \
      for (int k=0; k<3; k++){ \
        bf16x8 a_  = *(const bf16x8*)&w0s[((wave*4+n)*3 + k)*512 + lane*8]; \
        bf16x8 bb_ = *(const bf16x8*)&(XINB)[xbase0 ^ (k*32)]; \
        acc_ = MFMA_B16(a_, bb_, acc_); \
      } \
      int ob_ = (wave*4+n)*16 + fk*4; \
      u32x2 pw_ = { pk2(leaky(acc_[0]), leaky(acc_[1])), pk2(leaky(acc_[2]), leaky(acc_[3])) }; \
      *(u32x2*)&hF0[fm*WIDTH + (ob_ ^ (fm*8))] = pw_; \
    } \
    LBAR(); \
    { f32x4 acc_ = {0,0,0,0}; \
      _Pragma("unroll") \
      for (int kk=0; kk<16; kk++){ \
        bf16x8 bb_ = *(const bf16x8*)&hF0[hbase1 ^ (kk*32)]; \
        acc_ = MFMA_B16(w1f[kk], bb_, acc_); \
      } \
      unsigned lo0_ = pk2(leaky(acc_[0]+b1q[0]), leaky(acc_[1]+b1q[1])); \
      unsigned lo1_ = pk2(leaky(acc_[2]+b1q[2]), leaky(acc_[3]+b1q[3])); \
      (OWNQ) = (u64)lo0_ | ((u64)lo1_ << 32); \
      size_t mb_ = (size_t)((g*2+(T))*4 + j)*1024 + (size_t)(fm*32 + wave*4 + fk)*2; \
      u64 tg_ = ((u64)(unsigned)(S1)) << 32; \
      __hip_atomic_store(mbq + mb_,     (u64)lo0_ | tg_, __ATOMIC_RELAXED, __HIP_MEMORY_SCOPE_AGENT); \
      __hip_atomic_store(mbq + mb_ + 1, (u64)lo1_ | tg_, __ATOMIC_RELAXED, __HIP_MEMORY_SCOPE_AGENT); \
    } \
    LBAR(); \
  }while(0)

  // ---- G2: per-thread tagged poll+gather of peers' h1, then full l2 ----
  #define G2PHASE(T, OWNQ, S) do{ \
    const int br_ = t >> 5, cg_ = t & 31; \
    const size_t hb_ = (size_t)((g*2+(T))*4); \
    const size_t ia_ = (hb_+pm0)*1024 + (size_t)(br_*32+cg_)*2; \
    const size_t ib_ = (hb_+pm1)*1024 + (size_t)(br_*32+cg_)*2; \
    const size_t ic_ = (hb_+pm2)*1024 + (size_t)(br_*32+cg_)*2; \
    u64 a0_,a1_,b0_,b1_,c0_,c1_; int cnt_=0; \
    const unsigned s_ = (unsigned)(S); \
    for(;;){ \
      a0_ = __hip_atomic_load(mbq+ia_,   __ATOMIC_RELAXED, __HIP_MEMORY_SCOPE_AGENT); \
      a1_ = __hip_atomic_load(mbq+ia_+1, __ATOMIC_RELAXED, __HIP_MEMORY_SCOPE_AGENT); \
      b0_ = __hip_atomic_load(mbq+ib_,   __ATOMIC_RELAXED, __HIP_MEMORY_SCOPE_AGENT); \
      b1_ = __hip_atomic_load(mbq+ib_+1, __ATOMIC_RELAXED, __HIP_MEMORY_SCOPE_AGENT); \
      c0_ = __hip_atomic_load(mbq+ic_,   __ATOMIC_RELAXED, __HIP_MEMORY_SCOPE_AGENT); \
      c1_ = __hip_atomic_load(mbq+ic_+1, __ATOMIC_RELAXED, __HIP_MEMORY_SCOPE_AGENT); \
      if (((unsigned)(a0_>>32)==s_) & ((unsigned)(a1_>>32)==s_) & \
          ((unsigned)(b0_>>32)==s_) & ((unsigned)(b1_>>32)==s_) & \
          ((unsigned)(c0_>>32)==s_) & ((unsigned)(c1_>>32)==s_)) break; \
      if (*(volatile int*)&sdead) break; \
      __builtin_amdgcn_s_sleep(2); \
      if (++cnt_ > (1<<16)) { *(volatile int*)&sdead = 1; break; } \
    } \
    *(u64*)&hF1[fm*WIDTH + (chi ^ (fm*8))] = (OWNQ); \
    *(u64*)&hF1[br_*WIDTH + ((pm0*128 + cg_*4) ^ (br_*8))] = (u64)(unsigned)a0_ | ((u64)(unsigned)a1_ << 32); \
    *(u64*)&hF1[br_*WIDTH + ((pm1*128 + cg_*4) ^ (br_*8))] = (u64)(unsigned)b0_ | ((u64)(unsigned)b1_ << 32); \
    *(u64*)&hF1[br_*WIDTH + ((pm2*128 + cg_*4) ^ (br_*8))] = (u64)(unsigned)c0_ | ((u64)(unsigned)c1_ << 32); \
    LBAR(); \
    { f32x4 acc2_ = {0,0,0,0}; \
      _Pragma("unroll") \
      for (int kk=0; kk<16; kk++){ \
        bf16x8 bb_ = *(const bf16x8*)&hF1[hbase1 ^ (kk*32)]; \
        acc2_ = MFMA_B16(w2f[kk], bb_, acc2_); \
      } \
      u32x2 pw_ = { pk2(leaky(acc2_[0]+b2q[0]), leaky(acc2_[1]+b2q[1])), \
                    pk2(leaky(acc2_[2]+b2q[2]), leaky(acc2_[3]+b2q[3])) }; \
      *(u32x2*)&hF0[fm*WIDTH + (chi ^ (fm*8))] = pw_; \
    } \
    LBAR(); \
  }while(0)

  // ---- L3: own-K l3 partial + reduce + tagged dy publish ----
  #define L3PHASE(T, OWNV, S) do{ \
    { const int q_ = wave >> 1; \
      bf16x8 a_  = *(const bf16x8*)&w3s[wave*512 + lane*8]; \
      bf16x8 bb_ = *(const bf16x8*)&hF0[fm*WIDTH + ((j*128 + q_*32 + fk*8) ^ (fm*8))]; \
      f32x4 a3_ = MFMA_B16(a_, bb_, z4); \
      *(f32x4*)&pr[wave][fm][fk*4] = a3_; } \
    LBAR(); \
    { const int ntc_ = ucol >> 4, c15_ = ucol & 15; \
      (OWNV) = ((pr[ntc_][urow][c15_] + pr[2+ntc_][urow][c15_]) \
                + pr[4+ntc_][urow][c15_]) + pr[6+ntc_][urow][c15_]; \
      size_t db_ = DY_U64_BASE + (size_t)((g*2+(T))*4 + j)*512 + (size_t)(urow*32 + ucol); \
      __hip_atomic_store(mbq + db_, (u64)__float_as_uint(OWNV) | (((u64)(unsigned)(S)) << 32), \
                         __ATOMIC_RELAXED, __HIP_MEMORY_SCOPE_AGENT); } \
  }while(0)

  // ---- U: per-thread tagged dy poll, fixed-order sum, Euler, emit, reseed ----
  #define UPHASE(T, XINB, YSB, OUTP, OWNV, AV, S) do{ \
    const size_t db_ = DY_U64_BASE + (size_t)((g*2+(T))*4)*512 + (size_t)(urow*32 + ucol); \
    u64 va_,vb_,vc_; int cnt_=0; \
    const unsigned s_ = (unsigned)(S); \
    for(;;){ \
      va_ = __hip_atomic_load(mbq + db_ + (size_t)pm0*512, __ATOMIC_RELAXED, __HIP_MEMORY_SCOPE_AGENT); \
      vb_ = __hip_atomic_load(mbq + db_ + (size_t)pm1*512, __ATOMIC_RELAXED, __HIP_MEMORY_SCOPE_AGENT); \
      vc_ = __hip_atomic_load(mbq + db_ + (size_t)pm2*512, __ATOMIC_RELAXED, __HIP_MEMORY_SCOPE_AGENT); \
      if (((unsigned)(va_>>32)==s_) & ((unsigned)(vb_>>32)==s_) & ((unsigned)(vc_>>32)==s_)) break; \
      if (*(volatile int*)&sdead) break; \
      __builtin_amdgcn_s_sleep(2); \
      if (++cnt_ > (1<<16)) { *(volatile int*)&sdead = 1; break; } \
    } \
    float v0_ = __uint_as_float((unsigned)va_); \
    float v1_ = __uint_as_float((unsigned)vb_); \
    float v2_ = __uint_as_float((unsigned)vc_); \
    if (t < 128) (XINB)[xin_ac] = (bf16)(AV); \
    float a0_ = (j==0) ? (OWNV) : v0_; \
    float a1_ = (j==1) ? (OWNV) : ((j==0) ? v0_ : v1_); \
    float a2_ = (j==2) ? (OWNV) : ((j<2) ? v1_ : v2_); \
    float a3_ = (j==3) ? (OWNV) : v2_; \
    float dy_ = b3v + a0_ + a1_ + a2_ + a3_; \
    float yn_ = (YSB)[urow][ucol] + tauf * dy_; \
    (YSB)[urow][ucol] = yn_; \
    if (j == 0) (OUTP)[(size_t)(S)*OBS] = yn_; \
    bf16 yh_ = (bf16)yn_; \
    (XINB)[xin_yh] = yh_; \
    (XINB)[xin_yl] = (bf16)(yn_ - (float)yh_); \
    LBAR(); \
  }while(0)

  const f32x4 z4 = {0,0,0,0};
  u64 ownh1q0 = 0, ownh1q1 = 0;
  float ownv0 = 0.0f, ownv1 = 0.0f;

  // prologue: step-1 L01 for both tiles
  L01PHASE(0, xin0, ownh1q0, 1);
  L01PHASE(1, xin1, ownh1q1, 1);

  for (int s=1; s<=NSTEPS; ++s){
    const int aidx = (s < NSTEPS) ? s : 0;
    float av0 = actp0[(size_t)aidx*ACTD];
    float av1 = actp1[(size_t)aidx*ACTD];

    G2PHASE(0, ownh1q0, s);
    L3PHASE(0, ownv0, s);
    G2PHASE(1, ownh1q1, s);
    L3PHASE(1, ownv1, s);
    UPHASE(0, xin0, yS0, outp0, ownv0, av0, s);
    if (s < NSTEPS) L01PHASE(0, xin0, ownh1q0, s+1);
    UPHASE(1, xin1, yS1, outp1, ownv1, av1, s);
    if (s < NSTEPS) L01PHASE(1, xin1, ownh1q1, s+1);
  }
  asm volatile("s_waitcnt vmcnt(0) lgkmcnt(0)" ::: "memory");
}

extern "C" void kernel_launch(void* const* d_in, const int* in_sizes, int n_in,
                              void* d_out, int out_size, void* d_ws, size_t ws_size,
                              hipStream_t stream){
  const float* init_obs = (const float*)d_in[0];
  const float* actions  = (const float*)d_in[1];
  const float* W0 = (const float*)d_in[2];
  const float* b0 = (const float*)d_in[3];
  const float* W1 = (const float*)d_in[4];
  const float* b1 = (const float*)d_in[5];
  const float* W2 = (const float*)d_in[6];
  const float* b2 = (const float*)d_in[7];
  const float* W3 = (const float*)d_in[8];
  const float* b3 = (const float*)d_in[9];
  const int*  tau = (const int*)d_in[10];
  bf16* wsb = (bf16*)d_ws;
  float* out = (float*)d_out;

  hipLaunchKernelGGL(setup_kernel, dim3(512), dim3(256), 0, stream,
                     W0, b0, W1, W2, W3, tau, wsb);
  hipLaunchKernelGGL(ode_kernel, dim3(128), dim3(512), 0, stream,
                     init_obs, actions, b1, b2, b3, wsb, out);
}